// Round 4
// baseline (2108.745 us; speedup 1.0000x reference)
//
#include <hip/hip_runtime.h>

typedef __bf16 bf16;
typedef __bf16 bf16x4 __attribute__((ext_vector_type(4)));
typedef __bf16 bf16x8 __attribute__((ext_vector_type(8)));
typedef float f32x4 __attribute__((ext_vector_type(4)));
typedef unsigned int u32;
typedef unsigned short u16;

#define CL 2048
#define CN 4
#define CE 1024
#define CH 8

// ---------- async global->LDS, 16B per lane ----------
__device__ __forceinline__ void gload16(const bf16* g, bf16x8* l) {
  __builtin_amdgcn_global_load_lds((const __attribute__((address_space(1))) void*)g,
                                   (__attribute__((address_space(3))) void*)l, 16, 0, 0);
}

// ---------- 256xBN (BK=32) NT-GEMM mainloop, 512 threads = 8 waves (2M x 4N) ----------
// A: 256 rows x K (row-major, stride lda); B: BN rows x K (B^T, stride ldb).
// 4-buffer LDS ring, 2-tile-deep prefetch, ONE counted vmcnt + ONE barrier per K-tile.
// Ring-4 safety: staging for tile t+3 (issued after top-of-t barrier) reuses buffer
// (t-1)&3, whose readers all completed before that barrier (lgkmcnt before MFMA).
// XOR swizzle on the 16B-chunk index applied to BOTH global source and LDS read
// (global_load_lds dest stays linear) -> measured 0 bank conflicts.
template<int BN>
__device__ __forceinline__ void gemm_mainloop256(
    const bf16* __restrict__ Abase, const bf16* __restrict__ Bbase,
    int lda, int ldb, int nk, f32x4 (&acc)[8][BN / 64])
{
  constexpr int BJ = BN / 64;     // B fragments per wave (4 or 2)
  constexpr int BCH = BN * 4;     // 16B chunks per B tile
  __shared__ bf16x8 As[4][1024];
  __shared__ bf16x8 Bs[4][BCH];

  const int t = threadIdx.x;
  const int lane = t & 63;
  const int wid = t >> 6;
  const int wr = wid >> 2, wc = wid & 3;
  const int ln15 = lane & 15, kg = lane >> 4;

  int idxA[8], idxB[BJ];
#pragma unroll
  for (int i = 0; i < 8; ++i) {
    int row = wr * 128 + i * 16 + ln15;
    idxA[i] = row * 4 + (kg ^ ((row >> 1) & 3));
  }
#pragma unroll
  for (int j = 0; j < BJ; ++j) {
    int row = wc * (BN / 4) + j * 16 + ln15;
    idxB[j] = row * 4 + (kg ^ ((row >> 1) & 3));
  }

  // staging addresses (swizzled global source, linear LDS dest)
  const int ra0 = t >> 2;          const int ca0 = (t & 3) ^ ((ra0 >> 1) & 3);
  const int ra1 = (t + 512) >> 2;  const int ca1 = ((t + 512) & 3) ^ ((ra1 >> 1) & 3);
  const bf16* aS0 = Abase + (size_t)ra0 * lda + ca0 * 8;
  const bf16* aS1 = Abase + (size_t)ra1 * lda + ca1 * 8;
  const bf16* bS0 = Bbase + (size_t)ra0 * ldb + ca0 * 8;
  const bf16* bS1 = Bbase + (size_t)ra1 * ldb + ca1 * 8;  // used only when BN==256

  // prologue: stage tiles 0,1,2
#pragma unroll
  for (int pt = 0; pt < 3; ++pt) {
    gload16(aS0 + pt * 32, &As[pt][t]);
    gload16(aS1 + pt * 32, &As[pt][t + 512]);
    gload16(bS0 + pt * 32, &Bs[pt][t]);
    if constexpr (BN == 256) gload16(bS1 + pt * 32, &Bs[pt][t + 512]);
  }

  for (int kt = 0; kt < nk; ++kt) {
    const int rem = nk - 1 - kt;
    if constexpr (BN == 256) {
      if (rem >= 2)      asm volatile("s_waitcnt vmcnt(8)" ::: "memory");
      else if (rem == 1) asm volatile("s_waitcnt vmcnt(4)" ::: "memory");
      else               asm volatile("s_waitcnt vmcnt(0)" ::: "memory");
    } else {
      if (rem >= 2)      asm volatile("s_waitcnt vmcnt(6)" ::: "memory");
      else if (rem == 1) asm volatile("s_waitcnt vmcnt(3)" ::: "memory");
      else               asm volatile("s_waitcnt vmcnt(0)" ::: "memory");
    }
    __builtin_amdgcn_s_barrier();

    const int buf = kt & 3;
    const int nbuf = (kt + 3) & 3;
    const bool pf = (kt + 3) < nk;
    const int ko = (kt + 3) * 32;

    // ---- phase A: issue next A-tile loads, compute i = 0..3 ----
    if (pf) {
      gload16(aS0 + ko, &As[nbuf][t]);
      gload16(aS1 + ko, &As[nbuf][t + 512]);
    }
    bf16x8 bv[BJ], av[4];
#pragma unroll
    for (int j = 0; j < BJ; ++j) bv[j] = Bs[buf][idxB[j]];
#pragma unroll
    for (int i = 0; i < 4; ++i) av[i] = As[buf][idxA[i]];
    __builtin_amdgcn_s_setprio(1);
#pragma unroll
    for (int i = 0; i < 4; ++i)
#pragma unroll
      for (int j = 0; j < BJ; ++j)
        acc[i][j] = __builtin_amdgcn_mfma_f32_16x16x32_bf16(av[i], bv[j], acc[i][j], 0, 0, 0);
    __builtin_amdgcn_s_setprio(0);

    // ---- phase B: issue next B-tile loads, compute i = 4..7 ----
    if (pf) {
      gload16(bS0 + ko, &Bs[nbuf][t]);
      if constexpr (BN == 256) gload16(bS1 + ko, &Bs[nbuf][t + 512]);
    }
#pragma unroll
    for (int i = 0; i < 4; ++i) av[i] = As[buf][idxA[i + 4]];
    __builtin_amdgcn_s_setprio(1);
#pragma unroll
    for (int i = 0; i < 4; ++i)
#pragma unroll
      for (int j = 0; j < BJ; ++j)
        acc[i + 4][j] = __builtin_amdgcn_mfma_f32_16x16x32_bf16(av[i], bv[j], acc[i + 4][j], 0, 0, 0);
    __builtin_amdgcn_s_setprio(0);
  }
}

// ---------- kernels ----------
__global__ void k_cast(const float4* __restrict__ in, bf16x4* __restrict__ out, int n4) {
  int i = blockIdx.x * 256 + threadIdx.x;
  if (i < n4) {
    float4 v = in[i];
    bf16x4 o = {(bf16)v.x, (bf16)v.y, (bf16)v.z, (bf16)v.w};
    out[i] = o;
  }
}

// Per-head QKV projection: [8192,1024] @ Wh[3072,1024]^T; q/k/v each [n][L][E],
// Q pre-scaled by 1/32. Grid (32, 24), 512 threads.
__global__ __launch_bounds__(512, 2)
void k_qkv(const bf16* __restrict__ xb, const bf16* __restrict__ Whb,
           const float* __restrict__ bqkv3,
           bf16* __restrict__ qb, bf16* __restrict__ kb, bf16* __restrict__ vb)
{
  const int bm = blockIdx.x, bn = blockIdx.y;
  f32x4 acc[8][2] = {};
  const bf16* Ab = xb + (size_t)bm * 256 * CE;
  const bf16* Bb = Whb + (size_t)bn * 128 * CE;
  gemm_mainloop256<128>(Ab, Bb, CE, CE, CE / 32, acc);

  const int lane = threadIdx.x & 63, wid = threadIdx.x >> 6;
  const int wr = wid >> 2, wc = wid & 3, ln15 = lane & 15, kg = lane >> 4;
  const int f0 = bn * 128;
  bf16* dst; int e0; float scale = 1.0f;
  if (f0 < CE)          { dst = qb; e0 = f0;          scale = 0.03125f; }
  else if (f0 < 2 * CE) { dst = kb; e0 = f0 - CE; }
  else                  { dst = vb; e0 = f0 - 2 * CE; }
#pragma unroll
  for (int i = 0; i < 8; ++i)
#pragma unroll
    for (int r = 0; r < 4; ++r) {
      int m = bm * 256 + wr * 128 + i * 16 + kg * 4 + r;
      int l = m >> 2, n = m & 3;
      size_t rowbase = ((size_t)n * CL + l) * CE;
#pragma unroll
      for (int j = 0; j < 2; ++j) {
        int fo = wc * 32 + j * 16 + ln15;
        float v = acc[i][j][r] + bqkv3[f0 + fo];
        dst[rowbase + e0 + fo] = (bf16)(v * scale);
      }
    }
}

// V transpose per pair: [L][E] -> [E][L]
__global__ void k_transpose(const bf16* __restrict__ v, bf16* __restrict__ vt)
{
  __shared__ u16 s[64][66];
  const bf16* src = v + (size_t)blockIdx.z * CL * CE;
  bf16* dst = vt + (size_t)blockIdx.z * CE * CL;
  const int l0 = blockIdx.x * 64, e0 = blockIdx.y * 64;
  const int t = threadIdx.x;
#pragma unroll
  for (int rr = 0; rr < 2; ++rr) {
    int c = t + rr * 256;
    int row = c >> 3, cb = (c & 7) * 8;
    uint4 d = *(const uint4*)(src + (size_t)(l0 + row) * CE + e0 + cb);
    u32* sp = (u32*)&s[row][cb];
    sp[0] = d.x; sp[1] = d.y; sp[2] = d.z; sp[3] = d.w;
  }
  __syncthreads();
  const int erow = t >> 2, lc = (t & 3) * 16;
  u32 w[8];
#pragma unroll
  for (int q = 0; q < 8; ++q) {
    u16 a = s[lc + 2 * q][erow];
    u16 b = s[lc + 2 * q + 1][erow];
    w[q] = (u32)a | ((u32)b << 16);
  }
  bf16* dp = dst + (size_t)(e0 + erow) * CL + l0 + lc;
  ((uint4*)dp)[0] = make_uint4(w[0], w[1], w[2], w[3]);
  ((uint4*)dp)[1] = make_uint4(w[4], w[5], w[6], w[7]);
}

// S = Q @ K^T per pair (bf16 out). Grid (8, 8, 4), 512 threads.
__global__ __launch_bounds__(512, 2)
void k_scores(const bf16* __restrict__ qb, const bf16* __restrict__ kb,
              bf16* __restrict__ S)
{
  const int bm = blockIdx.x, bn = blockIdx.y, p = blockIdx.z;
  f32x4 acc[8][4] = {};
  const bf16* Ab = qb + (size_t)p * CL * CE + (size_t)bm * 256 * CE;
  const bf16* Bb = kb + (size_t)p * CL * CE + (size_t)bn * 256 * CE;
  gemm_mainloop256<256>(Ab, Bb, CE, CE, CE / 32, acc);

  const int lane = threadIdx.x & 63, wid = threadIdx.x >> 6;
  const int wr = wid >> 2, wc = wid & 3, ln15 = lane & 15, kg = lane >> 4;
  bf16* Sp = S + (size_t)p * CL * CL;
#pragma unroll
  for (int i = 0; i < 8; ++i)
#pragma unroll
    for (int r = 0; r < 4; ++r) {
      int row = bm * 256 + wr * 128 + i * 16 + kg * 4 + r;
#pragma unroll
      for (int j = 0; j < 4; ++j) {
        int col = bn * 256 + wc * 64 + j * 16 + ln15;
        Sp[(size_t)row * CL + col] = (bf16)acc[i][j][r];
      }
    }
}

// row softmax in place, one wave per row of 2048; 8192 rows total
__global__ __launch_bounds__(256)
void k_softmax(bf16* __restrict__ S)
{
  const int wid = threadIdx.x >> 6, lane = threadIdx.x & 63;
  const size_t row = (size_t)blockIdx.x * 4 + wid;
  ushort4* pv = (ushort4*)(S + row * CL);
  ushort4 d[8];
  float v[32];
#pragma unroll
  for (int c = 0; c < 8; ++c) d[c] = pv[c * 64 + lane];
#pragma unroll
  for (int c = 0; c < 8; ++c) {
    v[c*4+0] = __builtin_bit_cast(float, (u32)d[c].x << 16);
    v[c*4+1] = __builtin_bit_cast(float, (u32)d[c].y << 16);
    v[c*4+2] = __builtin_bit_cast(float, (u32)d[c].z << 16);
    v[c*4+3] = __builtin_bit_cast(float, (u32)d[c].w << 16);
  }
  float m = -1e30f;
#pragma unroll
  for (int i = 0; i < 32; ++i) m = fmaxf(m, v[i]);
#pragma unroll
  for (int o = 32; o; o >>= 1) m = fmaxf(m, __shfl_xor(m, o));
  float ssum = 0.f;
#pragma unroll
  for (int i = 0; i < 32; ++i) { v[i] = __expf(v[i] - m); ssum += v[i]; }
#pragma unroll
  for (int o = 32; o; o >>= 1) ssum += __shfl_xor(ssum, o);
  const float inv = 1.0f / ssum;
#pragma unroll
  for (int c = 0; c < 8; ++c) {
    ushort4 o;
    o.x = __builtin_bit_cast(u16, (bf16)(v[c*4+0] * inv));
    o.y = __builtin_bit_cast(u16, (bf16)(v[c*4+1] * inv));
    o.z = __builtin_bit_cast(u16, (bf16)(v[c*4+2] * inv));
    o.w = __builtin_bit_cast(u16, (bf16)(v[c*4+3] * inv));
    pv[c * 64 + lane] = o;
  }
}

// ctx = P @ V per pair; ctx [m = l*4+p][e] bf16 (aliases q). Grid (8, 8, 4).
__global__ __launch_bounds__(512, 2)
void k_pv(const bf16* __restrict__ S, const bf16* __restrict__ vt,
          bf16* __restrict__ ctx)
{
  const int bm = blockIdx.x, bn = blockIdx.y, p = blockIdx.z;
  f32x4 acc[8][2] = {};
  const bf16* Ab = S + (size_t)p * CL * CL + (size_t)bm * 256 * CL;
  const bf16* Bb = vt + (size_t)p * CE * CL + (size_t)bn * 128 * CL;
  gemm_mainloop256<128>(Ab, Bb, CL, CL, CL / 32, acc);

  const int lane = threadIdx.x & 63, wid = threadIdx.x >> 6;
  const int wr = wid >> 2, wc = wid & 3, ln15 = lane & 15, kg = lane >> 4;
#pragma unroll
  for (int i = 0; i < 8; ++i)
#pragma unroll
    for (int r = 0; r < 4; ++r) {
      int l = bm * 256 + wr * 128 + i * 16 + kg * 4 + r;
      int m = l * 4 + p;
#pragma unroll
      for (int j = 0; j < 2; ++j) {
        int e = bn * 128 + wc * 32 + j * 16 + ln15;
        ctx[(size_t)m * CE + e] = (bf16)acc[i][j][r];
      }
    }
}

// out[m][f] (+)= ctx @ Wo_h^T + bo_h. Grid (32, 8), 512 threads.
__global__ __launch_bounds__(512, 2)
void k_outproj(const bf16* __restrict__ ctx, const bf16* __restrict__ Wohb,
               const float* __restrict__ boh, float* __restrict__ out, int init)
{
  const int bm = blockIdx.x, bn = blockIdx.y;
  f32x4 acc[8][2] = {};
  const bf16* Ab = ctx + (size_t)bm * 256 * CE;
  const bf16* Bb = Wohb + (size_t)bn * 128 * CE;
  gemm_mainloop256<128>(Ab, Bb, CE, CE, CE / 32, acc);

  const int lane = threadIdx.x & 63, wid = threadIdx.x >> 6;
  const int wr = wid >> 2, wc = wid & 3, ln15 = lane & 15, kg = lane >> 4;
#pragma unroll
  for (int i = 0; i < 8; ++i)
#pragma unroll
    for (int r = 0; r < 4; ++r) {
      int m = bm * 256 + wr * 128 + i * 16 + kg * 4 + r;
#pragma unroll
      for (int j = 0; j < 2; ++j) {
        int f = bn * 128 + wc * 32 + j * 16 + ln15;
        size_t idx = (size_t)m * CE + f;
        float prev = init ? 0.0f : out[idx];
        out[idx] = prev + acc[i][j][r] + boh[f];
      }
    }
}

extern "C" void kernel_launch(void* const* d_in, const int* in_sizes, int n_in,
                              void* d_out, int out_size, void* d_ws, size_t ws_size,
                              hipStream_t stream) {
  const float* x    = (const float*)d_in[0];
  const float* Wqkv = (const float*)d_in[1];
  const float* bqkv = (const float*)d_in[2];
  const float* Wo   = (const float*)d_in[3];
  const float* bo   = (const float*)d_in[4];
  float* out = (float*)d_out;

  // workspace layout (bf16 elements), ~104 MB total
  bf16* xb   = (bf16*)d_ws;                      // 8192*1024
  bf16* Whb  = xb   + (size_t)8192 * 1024;       // 3072*1024
  bf16* Wohb = Whb  + (size_t)3072 * 1024;       // 1024*1024
  bf16* qb   = Wohb + (size_t)1024 * 1024;       // 4*2048*1024  [ctx aliases]
  bf16* kb   = qb   + (size_t)4 * 2048 * 1024;   // 4*2048*1024
  bf16* Sb   = kb   + (size_t)4 * 2048 * 1024;   // 4*2048*2048  [vb aliases]
  bf16* vtb  = Sb   + (size_t)4 * 2048 * 2048;   // 4*1024*2048
  bf16* vb   = Sb;
  bf16* ctx  = qb;

  const size_t needed = ((size_t)(8 + 3 + 1 + 8 + 8 + 16 + 8) * 1024 * 1024) * sizeof(bf16);
  if (ws_size < needed) return;

  k_cast<<<dim3(8192), 256, 0, stream>>>((const float4*)x, (bf16x4*)xb, 8192 * 1024 / 4);

  for (int h = 0; h < CH; ++h) {
    k_cast<<<dim3(3072), 256, 0, stream>>>((const float4*)(Wqkv + (size_t)h * 3072 * 1024),
                                           (bf16x4*)Whb, 3072 * 1024 / 4);
    k_cast<<<dim3(1024), 256, 0, stream>>>((const float4*)(Wo + (size_t)h * 1024 * 1024),
                                           (bf16x4*)Wohb, 1024 * 1024 / 4);
    k_qkv<<<dim3(32, 24), 512, 0, stream>>>(xb, Whb, bqkv + (size_t)h * 3 * CE, qb, kb, vb);
    k_transpose<<<dim3(32, 16, 4), 256, 0, stream>>>(vb, vtb);
    k_scores<<<dim3(8, 8, 4), 512, 0, stream>>>(qb, kb, Sb);
    k_softmax<<<dim3(2048), 256, 0, stream>>>(Sb);
    k_pv<<<dim3(8, 8, 4), 512, 0, stream>>>(Sb, vtb, ctx);
    k_outproj<<<dim3(32, 8), 512, 0, stream>>>(ctx, Wohb, bo + (size_t)h * CE, out, h == 0);
  }
}